// Round 4
// baseline (3652.803 us; speedup 1.0000x reference)
//
#include <hip/hip_runtime.h>

#define N_NODES 10000
#define SEQ_T   32
#define NF      128
#define GH      32
#define CH      64
#define LH      128
#define NE      160000
#define TS      31   // conv output / LSTM steps

__device__ __forceinline__ float sig_(float x){ return 1.f/(1.f + expf(-x)); }

// ---------------- degree count ----------------
__global__ void k_count(const int* __restrict__ dst, int* __restrict__ cnt){
    int e = blockIdx.x*256 + threadIdx.x;
    if (e < NE) atomicAdd(&cnt[dst[e]], 1);
}

__global__ void k_dinv(const int* __restrict__ cnt, float* __restrict__ dinv){
    int n = blockIdx.x*256 + threadIdx.x;
    if (n < N_NODES) dinv[n] = rsqrtf((float)(cnt[n] + 1));  // +1 self loop
}

// ---------------- exclusive scan (single block) ----------------
__global__ void k_scan(const int* __restrict__ cnt, int* __restrict__ rp, int* __restrict__ cur){
    __shared__ int buf[1024];
    __shared__ int carry;
    int tid = threadIdx.x;
    if (tid == 0) carry = 0;
    __syncthreads();
    for (int base = 0; base < N_NODES; base += 1024){
        int i = base + tid;
        int v = (i < N_NODES) ? cnt[i] : 0;
        buf[tid] = v;
        __syncthreads();
        for (int off = 1; off < 1024; off <<= 1){
            int t = (tid >= off) ? buf[tid-off] : 0;
            __syncthreads();
            buf[tid] += t;
            __syncthreads();
        }
        int incl = buf[tid];
        int tot  = buf[1023];
        int ex   = carry + incl - v;
        if (i < N_NODES){ rp[i] = ex; cur[i] = ex; }
        __syncthreads();
        if (tid == 0) carry += tot;
        __syncthreads();
    }
    if (tid == 0) rp[N_NODES] = carry;
}

// ---------------- scatter edges into CSR buckets ----------------
__global__ void k_scatter(const int* __restrict__ src, const int* __restrict__ dst,
                          int* __restrict__ cur, int* __restrict__ esrc){
    int e = blockIdx.x*256 + threadIdx.x;
    if (e < NE){
        int p = atomicAdd(&cur[dst[e]], 1);
        esrc[p] = src[e];
    }
}

// ---------------- GCN transform: hx[row][o] = sum_f x[row][f]*w[f][o] ----------------
__global__ __launch_bounds__(256) void k_xform(const float* __restrict__ x,
                                               const float* __restrict__ w,
                                               float* __restrict__ hx){
    int row = blockIdx.x*256 + threadIdx.x;            // 0 .. N*32-1
    if (row >= N_NODES*SEQ_T) return;
    const float4* xr = (const float4*)(x + (size_t)row*NF);
    float acc[GH];
    #pragma unroll
    for (int c = 0; c < GH; ++c) acc[c] = 0.f;
    for (int f4 = 0; f4 < NF/4; ++f4){
        float4 a = xr[f4];
        const float* wp = w + f4*4*GH;
        #pragma unroll
        for (int k = 0; k < 4; ++k){
            float av = ((const float*)&a)[k];
            #pragma unroll
            for (int c = 0; c < GH; ++c) acc[c] += av * wp[k*GH + c];
        }
    }
    float4* ho = (float4*)(hx + (size_t)row*GH);
    #pragma unroll
    for (int c4 = 0; c4 < GH/4; ++c4){
        float4 v; v.x = acc[c4*4+0]; v.y = acc[c4*4+1]; v.z = acc[c4*4+2]; v.w = acc[c4*4+3];
        ho[c4] = v;
    }
}

// ---------------- aggregation: one block per destination node ----------------
__global__ __launch_bounds__(256) void k_agg(const float* __restrict__ hx,
                                             const int* __restrict__ rp,
                                             const int* __restrict__ esrc,
                                             const float* __restrict__ dinv,
                                             const float* __restrict__ bias,
                                             float* __restrict__ g){
    int d  = blockIdx.x;
    int t4 = threadIdx.x;                 // float4 slot 0..255 (1024 floats per node)
    float dv = dinv[d];
    float sn = dv*dv;                      // self-loop norm
    float4 a = ((const float4*)(hx + (size_t)d*1024))[t4];
    float4 acc; acc.x = a.x*sn; acc.y = a.y*sn; acc.z = a.z*sn; acc.w = a.w*sn;
    int beg = rp[d], end = rp[d+1];
    for (int e = beg; e < end; ++e){
        int s = esrc[e];
        float nr = dinv[s]*dv;
        float4 v = ((const float4*)(hx + (size_t)s*1024))[t4];
        acc.x += v.x*nr; acc.y += v.y*nr; acc.z += v.z*nr; acc.w += v.w*nr;
    }
    float4 b4 = ((const float4*)bias)[t4 & 7];   // channel = (t4*4)%32
    acc.x = fmaxf(acc.x + b4.x, 0.f);
    acc.y = fmaxf(acc.y + b4.y, 0.f);
    acc.z = fmaxf(acc.z + b4.z, 0.f);
    acc.w = fmaxf(acc.w + b4.w, 0.f);
    ((float4*)(g + (size_t)d*1024))[t4] = acc;
}

// ---------------- conv weight re-layout: wr[i][o], i in 0..63 ----------------
__global__ void k_wprep(const float* __restrict__ cw, float* __restrict__ wr){
    int idx = blockIdx.x*256 + threadIdx.x;
    if (idx < 64*64){
        int o = idx >> 6, i = idx & 63;
        wr[i*64 + o] = cw[o*64 + (i & 31)*2 + (i >> 5)];
    }
}

// ---------------- conv1d as thread-per-row GEMM ----------------
__global__ __launch_bounds__(256) void k_conv(const float* __restrict__ g,
                                              const float* __restrict__ wr,
                                              const float* __restrict__ cb,
                                              float* __restrict__ seq){
    int m = blockIdx.x*256 + threadIdx.x;              // row = n*31 + t
    if (m >= N_NODES*TS) return;
    int n = m / TS;
    int t = m - n*TS;
    // A row = g[n][t][0..31] ++ g[n][t+1][0..31]  (contiguous 64 floats)
    const float4* ar = (const float4*)(g + ((size_t)n*SEQ_T + t)*GH);
    float acc[CH];
    #pragma unroll
    for (int o = 0; o < CH; ++o) acc[o] = 0.f;
    for (int f4 = 0; f4 < 16; ++f4){
        float4 a = ar[f4];
        #pragma unroll
        for (int k = 0; k < 4; ++k){
            float av = ((const float*)&a)[k];
            const float* wrow = wr + (f4*4 + k)*CH;
            #pragma unroll
            for (int o = 0; o < CH; ++o) acc[o] += av * wrow[o];
        }
    }
    float* so = seq + (size_t)t*(N_NODES*CH) + (size_t)n*CH;   // layout [t][n][64]
    #pragma unroll
    for (int o4 = 0; o4 < CH/4; ++o4){
        float4 v;
        v.x = fmaxf(acc[o4*4+0] + cb[o4*4+0], 0.f);
        v.y = fmaxf(acc[o4*4+1] + cb[o4*4+1], 0.f);
        v.z = fmaxf(acc[o4*4+2] + cb[o4*4+2], 0.f);
        v.w = fmaxf(acc[o4*4+3] + cb[o4*4+3], 0.f);
        ((float4*)so)[o4] = v;
    }
}

// ---------------- recurrent LSTM step (input projection fused) ----------------
// gates[r][n] = sum_k xt[n][k]*wih[r][k] + sum_k h[n][k]*whh[r][k] + bih[r]+bhh[r]
// block: 256 thr = 4 waves x 64 lanes(=nodes); wave owns 8 j's x 4 gates = 32 accs.
// grid: (ceil(N/64), 4); wave wv in block y handles jb = y*32+wv*8 .. +7 -> j 0..127.
__global__ __launch_bounds__(256) void k_step(const float* __restrict__ xt,  // [N][64]
                                              const float* __restrict__ hin, // [128][N]
                                              float* __restrict__ hout,      // [128][N]
                                              float* __restrict__ cst,       // [128][N]
                                              const float* __restrict__ wih, // [512][64]
                                              const float* __restrict__ whh, // [512][128]
                                              const float* __restrict__ bih,
                                              const float* __restrict__ bhh){
    __shared__ float xs[64*65];
    __shared__ float hs[64*129];
    int tid = threadIdx.x, lane = tid & 63, wv = tid >> 6;
    int n0 = blockIdx.x * 64;
    for (int idx = tid; idx < 64*64; idx += 256){
        int nl = idx >> 6, c = idx & 63;
        int n = n0 + nl;
        xs[nl*65 + c] = (n < N_NODES) ? xt[(size_t)n*64 + c] : 0.f;
    }
    for (int idx = tid; idx < 64*128; idx += 256){
        int k = idx >> 6, nl = idx & 63;
        int n = n0 + nl;
        hs[nl*129 + k] = (n < N_NODES) ? hin[(size_t)k*N_NODES + n] : 0.f;
    }
    __syncthreads();

    int jb = __builtin_amdgcn_readfirstlane((int)blockIdx.y*32 + wv*8);
    int n  = n0 + lane;

    float acc[8][4];
    #pragma unroll
    for (int q = 0; q < 8; ++q)
        #pragma unroll
        for (int gg = 0; gg < 4; ++gg)
            acc[q][gg] = bih[gg*128 + jb + q] + bhh[gg*128 + jb + q];

    const float* xrow = xs + lane*65;
    const float* hrow = hs + lane*129;

    #pragma unroll 4
    for (int k = 0; k < 64; ++k){
        float v = xrow[k];
        #pragma unroll
        for (int q = 0; q < 8; ++q)
            #pragma unroll
            for (int gg = 0; gg < 4; ++gg)
                acc[q][gg] += v * wih[(size_t)(gg*128 + jb + q)*64 + k];
    }
    #pragma unroll 4
    for (int k = 0; k < 128; ++k){
        float v = hrow[k];
        #pragma unroll
        for (int q = 0; q < 8; ++q)
            #pragma unroll
            for (int gg = 0; gg < 4; ++gg)
                acc[q][gg] += v * whh[(size_t)(gg*128 + jb + q)*128 + k];
    }

    if (n < N_NODES){
        #pragma unroll
        for (int q = 0; q < 8; ++q){
            int j = jb + q;
            float ig = sig_(acc[q][0]);
            float fg = sig_(acc[q][1]);
            float gv = tanhf(acc[q][2]);
            float og = sig_(acc[q][3]);
            float cp = cst[(size_t)j*N_NODES + n];
            float cn = fg*cp + ig*gv;
            cst [(size_t)j*N_NODES + n] = cn;
            hout[(size_t)j*N_NODES + n] = og * tanhf(cn);
        }
    }
}

// ---------------- MLP head ----------------
__global__ __launch_bounds__(256) void k_head(const float* __restrict__ hl,   // [128][N]
                                              const float* __restrict__ w1,   // [128][64]
                                              const float* __restrict__ b1,
                                              const float* __restrict__ w2,   // [64][128]
                                              const float* __restrict__ b2,
                                              float* __restrict__ out){       // [N][128]
    __shared__ float hsl[64*129];
    __shared__ float y1 [64*65];
    int tid = threadIdx.x;
    int n0  = blockIdx.x*64;
    for (int idx = tid; idx < 64*128; idx += 256){
        int k = idx >> 6, nl = idx & 63;
        int n = n0 + nl;
        hsl[nl*129 + k] = (n < N_NODES) ? hl[(size_t)k*N_NODES + n] : 0.f;
    }
    __syncthreads();
    for (int rep = 0; rep < 16; ++rep){
        int id = rep*256 + tid;
        int nl = id >> 6, c = id & 63;
        float a = b1[c];
        #pragma unroll 4
        for (int k = 0; k < 128; ++k) a += hsl[nl*129 + k] * w1[k*64 + c];
        y1[nl*65 + c] = fmaxf(a, 0.f);
    }
    __syncthreads();
    for (int rep = 0; rep < 32; ++rep){
        int id = rep*256 + tid;
        int nl = id >> 7, o = id & 127;
        int n = n0 + nl;
        float a = b2[o];
        #pragma unroll 4
        for (int k = 0; k < 64; ++k) a += y1[nl*65 + k] * w2[k*128 + o];
        if (n < N_NODES) out[(size_t)n*128 + o] = a;
    }
}

extern "C" void kernel_launch(void* const* d_in, const int* in_sizes, int n_in,
                              void* d_out, int out_size, void* d_ws, size_t ws_size,
                              hipStream_t stream){
    const float* x      = (const float*)d_in[0];
    const int*   ei     = (const int*)  d_in[1];
    const float* gcn_w  = (const float*)d_in[2];
    const float* gcn_b  = (const float*)d_in[3];
    const float* conv_w = (const float*)d_in[4];
    const float* conv_b = (const float*)d_in[5];
    const float* w_ih   = (const float*)d_in[6];
    const float* w_hh   = (const float*)d_in[7];
    const float* b_ih   = (const float*)d_in[8];
    const float* b_hh   = (const float*)d_in[9];
    const float* fc1_w  = (const float*)d_in[10];
    const float* fc1_b  = (const float*)d_in[11];
    const float* fc2_w  = (const float*)d_in[12];
    const float* fc2_b  = (const float*)d_in[13];
    float* out = (float*)d_out;

    char* p = (char*)d_ws;
    auto alloc = [&](size_t bytes)->void*{ void* r = p; p += (bytes + 255) & ~(size_t)255; return r; };
    float* dinv = (float*)alloc(N_NODES*4);
    int*   cnt  = (int*)  alloc((N_NODES+1)*4);
    int*   rp   = (int*)  alloc((N_NODES+1)*4);
    int*   cur  = (int*)  alloc(N_NODES*4);
    int*   esrc = (int*)  alloc(NE*4);
    float* hx   = (float*)alloc((size_t)N_NODES*SEQ_T*GH*4);    // 40.96 MB
    float* g    = (float*)alloc((size_t)N_NODES*SEQ_T*GH*4);    // 40.96 MB
    float* seq  = (float*)alloc((size_t)TS*N_NODES*CH*4);       // 79.36 MB
    float* hA   = (float*)alloc((size_t)LH*N_NODES*4);          // 5.12 MB
    float* hB   = (float*)alloc((size_t)LH*N_NODES*4);
    float* cs   = (float*)alloc((size_t)LH*N_NODES*4);
    float* wr   = (float*)alloc(64*64*4);
    // total ~177 MB, no aliasing

    hipMemsetAsync(cnt, 0, (N_NODES+1)*4, stream);
    hipMemsetAsync(hA,  0, (size_t)LH*N_NODES*4, stream);
    hipMemsetAsync(cs,  0, (size_t)LH*N_NODES*4, stream);

    const int* e_src = ei;
    const int* e_dst = ei + NE;

    k_count  <<<(NE+255)/256, 256, 0, stream>>>(e_dst, cnt);
    k_dinv   <<<(N_NODES+255)/256, 256, 0, stream>>>(cnt, dinv);
    k_scan   <<<1, 1024, 0, stream>>>(cnt, rp, cur);
    k_scatter<<<(NE+255)/256, 256, 0, stream>>>(e_src, e_dst, cur, esrc);

    k_xform  <<<(N_NODES*SEQ_T+255)/256, 256, 0, stream>>>(x, gcn_w, hx);
    k_agg    <<<N_NODES, 256, 0, stream>>>(hx, rp, esrc, dinv, gcn_b, g);

    k_wprep  <<<16, 256, 0, stream>>>(conv_w, wr);
    k_conv   <<<(N_NODES*TS+255)/256, 256, 0, stream>>>(g, wr, conv_b, seq);

    dim3 sgrid((N_NODES+63)/64, 4);
    for (int t = 0; t < TS; ++t){
        const float* hin = (t & 1) ? hB : hA;
        float*       ho  = (t & 1) ? hA : hB;
        k_step<<<sgrid, 256, 0, stream>>>(seq + (size_t)t*N_NODES*CH, hin, ho, cs,
                                          w_ih, w_hh, b_ih, b_hh);
    }
    // TS=31 odd -> last write went to hB (t=30 even)
    k_head<<<(N_NODES+63)/64, 256, 0, stream>>>(hB, fc1_w, fc1_b, fc2_w, fc2_b, out);
}

// Round 5
// 1965.876 us; speedup vs baseline: 1.8581x; 1.8581x over previous
//
#include <hip/hip_runtime.h>

#define N_NODES 10000
#define NPAD    10112   // 79 * 128
#define SEQ_T   32
#define NF      128
#define GH      32
#define CH      64
#define LH      128
#define NE      160000
#define TS      31      // conv output / LSTM steps

typedef __attribute__((ext_vector_type(8))) short  bf16x8;
typedef __attribute__((ext_vector_type(4))) float  f32x4;

__device__ __forceinline__ float sig_(float x){ return 1.f/(1.f + expf(-x)); }
__device__ __forceinline__ unsigned short f2bf(float f){
    unsigned int u = __float_as_uint(f);
    u += 0x7FFF + ((u>>16)&1);
    return (unsigned short)(u>>16);
}
__device__ __forceinline__ float bf2f(unsigned short h){
    return __uint_as_float(((unsigned int)h)<<16);
}

// ---------------- degree count ----------------
__global__ void k_count(const int* __restrict__ dst, int* __restrict__ cnt){
    int e = blockIdx.x*256 + threadIdx.x;
    if (e < NE) atomicAdd(&cnt[dst[e]], 1);
}

__global__ void k_dinv(const int* __restrict__ cnt, float* __restrict__ dinv){
    int n = blockIdx.x*256 + threadIdx.x;
    if (n < N_NODES) dinv[n] = rsqrtf((float)(cnt[n] + 1));  // +1 self loop
}

// ---------------- exclusive scan (single block) ----------------
__global__ void k_scan(const int* __restrict__ cnt, int* __restrict__ rp, int* __restrict__ cur){
    __shared__ int buf[1024];
    __shared__ int carry;
    int tid = threadIdx.x;
    if (tid == 0) carry = 0;
    __syncthreads();
    for (int base = 0; base < N_NODES; base += 1024){
        int i = base + tid;
        int v = (i < N_NODES) ? cnt[i] : 0;
        buf[tid] = v;
        __syncthreads();
        for (int off = 1; off < 1024; off <<= 1){
            int t = (tid >= off) ? buf[tid-off] : 0;
            __syncthreads();
            buf[tid] += t;
            __syncthreads();
        }
        int incl = buf[tid];
        int tot  = buf[1023];
        int ex   = carry + incl - v;
        if (i < N_NODES){ rp[i] = ex; cur[i] = ex; }
        __syncthreads();
        if (tid == 0) carry += tot;
        __syncthreads();
    }
    if (tid == 0) rp[N_NODES] = carry;
}

// ---------------- scatter edges into CSR buckets ----------------
__global__ void k_scatter(const int* __restrict__ src, const int* __restrict__ dst,
                          int* __restrict__ cur, int* __restrict__ esrc){
    int e = blockIdx.x*256 + threadIdx.x;
    if (e < NE){
        int p = atomicAdd(&cur[dst[e]], 1);
        esrc[p] = src[e];
    }
}

// ---------------- GCN transform, LDS-tiled: hx[row][o] = sum_f x[row][f]*w[f][o] ----
// block = 256 thr, 64 rows. 5000 blocks (320000 rows exactly).
__global__ __launch_bounds__(256) void k_xform(const float* __restrict__ x,
                                               const float* __restrict__ w,
                                               float* __restrict__ hx){
    __shared__ float xls[64*129];
    int tid = threadIdx.x;
    size_t row0 = (size_t)blockIdx.x * 64;
    #pragma unroll
    for (int it = 0; it < 8; ++it){
        int idx = it*256 + tid;            // 64*32 float4 slots
        int r = idx >> 5, c4 = idx & 31;
        float4 v = *(const float4*)(x + (row0 + r)*NF + c4*4);
        xls[r*129 + c4*4 + 0] = v.x;
        xls[r*129 + c4*4 + 1] = v.y;
        xls[r*129 + c4*4 + 2] = v.z;
        xls[r*129 + c4*4 + 3] = v.w;
    }
    __syncthreads();
    int nl = tid & 63;
    int cg = __builtin_amdgcn_readfirstlane(tid >> 6);   // wave-uniform col group
    float acc[8];
    #pragma unroll
    for (int j = 0; j < 8; ++j) acc[j] = 0.f;
    const float* xrow = xls + nl*129;
    #pragma unroll 4
    for (int k = 0; k < NF; ++k){
        float v = xrow[k];
        const float* wp = w + k*GH + cg*8;   // wave-uniform -> scalar loads
        #pragma unroll
        for (int j = 0; j < 8; ++j) acc[j] += v * wp[j];
    }
    float* ho = hx + (row0 + nl)*GH + cg*8;
    float4 v0; v0.x=acc[0]; v0.y=acc[1]; v0.z=acc[2]; v0.w=acc[3];
    float4 v1; v1.x=acc[4]; v1.y=acc[5]; v1.z=acc[6]; v1.w=acc[7];
    ((float4*)ho)[0] = v0;
    ((float4*)ho)[1] = v1;
}

// ---------------- aggregation: one block per destination node ----------------
__global__ __launch_bounds__(256) void k_agg(const float* __restrict__ hx,
                                             const int* __restrict__ rp,
                                             const int* __restrict__ esrc,
                                             const float* __restrict__ dinv,
                                             const float* __restrict__ bias,
                                             float* __restrict__ g){
    int d  = blockIdx.x;
    int t4 = threadIdx.x;                 // float4 slot 0..255 (1024 floats per node)
    float dv = dinv[d];
    float sn = dv*dv;                      // self-loop norm
    float4 a = ((const float4*)(hx + (size_t)d*1024))[t4];
    float4 acc; acc.x = a.x*sn; acc.y = a.y*sn; acc.z = a.z*sn; acc.w = a.w*sn;
    int beg = rp[d], end = rp[d+1];
    for (int e = beg; e < end; ++e){
        int s = esrc[e];
        float nr = dinv[s]*dv;
        float4 v = ((const float4*)(hx + (size_t)s*1024))[t4];
        acc.x += v.x*nr; acc.y += v.y*nr; acc.z += v.z*nr; acc.w += v.w*nr;
    }
    float4 b4 = ((const float4*)bias)[t4 & 7];   // channel = (t4*4)%32
    acc.x = fmaxf(acc.x + b4.x, 0.f);
    acc.y = fmaxf(acc.y + b4.y, 0.f);
    acc.z = fmaxf(acc.z + b4.z, 0.f);
    acc.w = fmaxf(acc.w + b4.w, 0.f);
    ((float4*)(g + (size_t)d*1024))[t4] = acc;
}

// ---------------- conv weight re-layout: wr[i][o], i in 0..63 ----------------
__global__ void k_wprep(const float* __restrict__ cw, float* __restrict__ wr){
    int idx = blockIdx.x*256 + threadIdx.x;
    if (idx < 64*64){
        int o = idx >> 6, i = idx & 63;
        wr[i*64 + o] = cw[o*64 + (i & 31)*2 + (i >> 5)];
    }
}

// ---------------- LSTM weight prep: row' = j*4+gate order, bf16 hi/lo split ------
__global__ void k_wprep2(const float* __restrict__ wih, const float* __restrict__ whh,
                         const float* __restrict__ bih, const float* __restrict__ bhh,
                         unsigned short* __restrict__ Whi, unsigned short* __restrict__ Wlo,
                         float* __restrict__ bsum){
    int e = blockIdx.x*256 + threadIdx.x;   // 512*192 = 98304
    if (e >= 512*192) return;
    int rp = e / 192, k = e - rp*192;
    int j = rp >> 2, gt = rp & 3, R = gt*128 + j;
    float v = (k < 64) ? wih[R*64 + k] : whh[R*128 + (k-64)];
    unsigned short hi = f2bf(v);
    Whi[e] = hi;
    Wlo[e] = f2bf(v - bf2f(hi));
    if (k == 0) bsum[rp] = bih[R] + bhh[R];
}

// ---------------- conv1d, thread-per-row; writes bf16 hi/lo node-major Xt --------
__global__ __launch_bounds__(256) void k_conv(const float* __restrict__ g,
                                              const float* __restrict__ wr,
                                              const float* __restrict__ cb,
                                              unsigned short* __restrict__ Xth,
                                              unsigned short* __restrict__ Xtl){
    int m = blockIdx.x*256 + threadIdx.x;              // row = n*31 + t
    if (m >= N_NODES*TS) return;
    int n = m / TS;
    int t = m - n*TS;
    const float4* ar = (const float4*)(g + ((size_t)n*SEQ_T + t)*GH);
    float acc[CH];
    #pragma unroll
    for (int o = 0; o < CH; ++o) acc[o] = 0.f;
    for (int f4 = 0; f4 < 16; ++f4){
        float4 a = ar[f4];
        #pragma unroll
        for (int k = 0; k < 4; ++k){
            float av = ((const float*)&a)[k];
            const float* wrow = wr + (f4*4 + k)*CH;
            #pragma unroll
            for (int o = 0; o < CH; ++o) acc[o] += av * wrow[o];
        }
    }
    size_t base = ((size_t)t*NPAD + n)*CH;
    #pragma unroll
    for (int o4 = 0; o4 < CH/4; ++o4){
        ushort4 vh, vl;
        float v0 = fmaxf(acc[o4*4+0] + cb[o4*4+0], 0.f);
        float v1 = fmaxf(acc[o4*4+1] + cb[o4*4+1], 0.f);
        float v2 = fmaxf(acc[o4*4+2] + cb[o4*4+2], 0.f);
        float v3 = fmaxf(acc[o4*4+3] + cb[o4*4+3], 0.f);
        vh.x = f2bf(v0); vl.x = f2bf(v0 - bf2f(vh.x));
        vh.y = f2bf(v1); vl.y = f2bf(v1 - bf2f(vh.y));
        vh.z = f2bf(v2); vl.z = f2bf(v2 - bf2f(vh.z));
        vh.w = f2bf(v3); vl.w = f2bf(v3 - bf2f(vh.w));
        *(ushort4*)(Xth + base + o4*4) = vh;
        *(ushort4*)(Xtl + base + o4*4) = vl;
    }
}

// ---------------- MFMA LSTM step: gates = Wcat @ [x_t; h] (split-bf16, 3 terms) ---
// grid (79, 8), block 256 = 4 waves. Wave: 16 rows' (=4 j x 4 gates) x 128 nodes.
// A: Wcat[512][192] rows' j*4+gate. B: Xt[n][64] (k<64), Hin[n][128] (k>=64).
// C tile: lane: col(n) = l&15, row' = (l>>4)*4 + reg -> reg = gate, j_l = l>>4.
__global__ __launch_bounds__(256) void k_step(const unsigned short* __restrict__ Xth,
                                              const unsigned short* __restrict__ Xtl,
                                              const unsigned short* __restrict__ Hih,
                                              const unsigned short* __restrict__ Hil,
                                              unsigned short* __restrict__ Hoh,
                                              unsigned short* __restrict__ Hol,
                                              float* __restrict__ cst,        // [128][NPAD]
                                              const unsigned short* __restrict__ Whi,
                                              const unsigned short* __restrict__ Wlo,
                                              const float* __restrict__ bsum){
    __shared__ unsigned short lds_h[128*16*2];   // hi then lo halves
    int tid  = threadIdx.x;
    int lane = tid & 63, wv = tid >> 6;
    int n_base = blockIdx.x * 128;
    int by  = blockIdx.y;
    int r0  = by*64 + wv*16;          // global row' base of this wave's tile
    int ar  = lane & 15;              // A-row / B-col within tile
    int kg  = lane >> 4;

    f32x4 acc[8];
    #pragma unroll
    for (int i = 0; i < 8; ++i) acc[i] = (f32x4){0.f,0.f,0.f,0.f};

    const unsigned short* Ah = Whi + (size_t)(r0 + ar)*192 + kg*8;
    const unsigned short* Al = Wlo + (size_t)(r0 + ar)*192 + kg*8;

    #pragma unroll
    for (int kc = 0; kc < 6; ++kc){
        int kp = kc*32;
        bf16x8 ahi = *(const bf16x8*)(Ah + kp);
        bf16x8 alo = *(const bf16x8*)(Al + kp);
        const unsigned short* Bh;
        const unsigned short* Bl;
        int stride;
        if (kc < 2){ Bh = Xth + kp + kg*8;        Bl = Xtl + kp + kg*8;        stride = 64;  }
        else       { Bh = Hih + (kp-64) + kg*8;   Bl = Hil + (kp-64) + kg*8;   stride = 128; }
        #pragma unroll
        for (int nt = 0; nt < 8; ++nt){
            size_t n = n_base + nt*16 + ar;
            bf16x8 bhi = *(const bf16x8*)(Bh + n*stride);
            bf16x8 blo = *(const bf16x8*)(Bl + n*stride);
            acc[nt] = __builtin_amdgcn_mfma_f32_16x16x32_bf16(ahi, bhi, acc[nt], 0, 0, 0);
            acc[nt] = __builtin_amdgcn_mfma_f32_16x16x32_bf16(ahi, blo, acc[nt], 0, 0, 0);
            acc[nt] = __builtin_amdgcn_mfma_f32_16x16x32_bf16(alo, bhi, acc[nt], 0, 0, 0);
        }
    }

    int jl = wv*4 + (lane>>4);        // j_local 0..15
    int j  = by*16 + jl;              // global j
    float4 bs = ((const float4*)bsum)[j];
    #pragma unroll
    for (int nt = 0; nt < 8; ++nt){
        int n = n_base + nt*16 + (lane & 15);
        float ig = sig_(acc[nt][0] + bs.x);
        float fg = sig_(acc[nt][1] + bs.y);
        float gv = tanhf(acc[nt][2] + bs.z);
        float og = sig_(acc[nt][3] + bs.w);
        float cold = cst[(size_t)j*NPAD + n];
        float cn = fg*cold + ig*gv;
        cst[(size_t)j*NPAD + n] = cn;
        float h = og * tanhf(cn);
        unsigned short hh = f2bf(h);
        unsigned short hl = f2bf(h - bf2f(hh));
        int nl = nt*16 + (lane & 15);
        lds_h[nl*16 + jl]        = hh;
        lds_h[2048 + nl*16 + jl] = hl;
    }
    __syncthreads();
    // coalesced write-out: 16 j's (32 B) per node row, hi and lo
    int nl2 = tid >> 1, hf2 = tid & 1;
    size_t n2 = (size_t)n_base + nl2;
    uint4 vhi = *(const uint4*)(lds_h + nl2*16 + hf2*8);
    uint4 vlo = *(const uint4*)(lds_h + 2048 + nl2*16 + hf2*8);
    *(uint4*)(Hoh + n2*128 + by*16 + hf2*8) = vhi;
    *(uint4*)(Hol + n2*128 + by*16 + hf2*8) = vlo;
}

// ---------------- MLP head (reads h from bf16 hi/lo, node-major) ----------------
__global__ __launch_bounds__(256) void k_head(const unsigned short* __restrict__ Hh,
                                              const unsigned short* __restrict__ Hl,
                                              const float* __restrict__ w1,   // [128][64]
                                              const float* __restrict__ b1,
                                              const float* __restrict__ w2,   // [64][128]
                                              const float* __restrict__ b2,
                                              float* __restrict__ out){       // [N][128]
    __shared__ float hsl[64*129];
    __shared__ float y1 [64*65];
    int tid = threadIdx.x;
    int n0  = blockIdx.x*64;
    for (int idx = tid; idx < 64*128; idx += 256){
        int nl = idx >> 7, k = idx & 127;
        int n = n0 + nl;
        float v = 0.f;
        if (n < N_NODES){
            v = bf2f(Hh[(size_t)n*128 + k]) + bf2f(Hl[(size_t)n*128 + k]);
        }
        hsl[nl*129 + k] = v;
    }
    __syncthreads();
    for (int rep = 0; rep < 16; ++rep){
        int id = rep*256 + tid;
        int nl = id >> 6, c = id & 63;
        float a = b1[c];
        #pragma unroll 4
        for (int k = 0; k < 128; ++k) a += hsl[nl*129 + k] * w1[k*64 + c];
        y1[nl*65 + c] = fmaxf(a, 0.f);
    }
    __syncthreads();
    for (int rep = 0; rep < 32; ++rep){
        int id = rep*256 + tid;
        int nl = id >> 7, o = id & 127;
        int n = n0 + nl;
        float a = b2[o];
        #pragma unroll 4
        for (int k = 0; k < 64; ++k) a += y1[nl*65 + k] * w2[k*128 + o];
        if (n < N_NODES) out[(size_t)n*128 + o] = a;
    }
}

extern "C" void kernel_launch(void* const* d_in, const int* in_sizes, int n_in,
                              void* d_out, int out_size, void* d_ws, size_t ws_size,
                              hipStream_t stream){
    const float* x      = (const float*)d_in[0];
    const int*   ei     = (const int*)  d_in[1];
    const float* gcn_w  = (const float*)d_in[2];
    const float* gcn_b  = (const float*)d_in[3];
    const float* conv_w = (const float*)d_in[4];
    const float* conv_b = (const float*)d_in[5];
    const float* w_ih   = (const float*)d_in[6];
    const float* w_hh   = (const float*)d_in[7];
    const float* b_ih   = (const float*)d_in[8];
    const float* b_hh   = (const float*)d_in[9];
    const float* fc1_w  = (const float*)d_in[10];
    const float* fc1_b  = (const float*)d_in[11];
    const float* fc2_w  = (const float*)d_in[12];
    const float* fc2_b  = (const float*)d_in[13];
    float* out = (float*)d_out;

    char* p = (char*)d_ws;
    auto alloc = [&](size_t bytes)->void*{ void* r = p; p += (bytes + 255) & ~(size_t)255; return r; };
    float* dinv = (float*)alloc(N_NODES*4);
    int*   cnt  = (int*)  alloc((N_NODES+1)*4);
    int*   rp   = (int*)  alloc((N_NODES+1)*4);
    int*   cur  = (int*)  alloc(N_NODES*4);
    int*   esrc = (int*)  alloc(NE*4);
    float* hx   = (float*)alloc((size_t)N_NODES*SEQ_T*GH*4);          // 40.96 MB
    float* g    = (float*)alloc((size_t)N_NODES*SEQ_T*GH*4);          // 40.96 MB
    unsigned short* Xth = (unsigned short*)alloc((size_t)TS*NPAD*CH*2); // 40.1 MB
    unsigned short* Xtl = (unsigned short*)alloc((size_t)TS*NPAD*CH*2); // 40.1 MB
    unsigned short* HAh = (unsigned short*)alloc((size_t)NPAD*LH*2);    // 2.59 MB
    unsigned short* HAl = (unsigned short*)alloc((size_t)NPAD*LH*2);
    unsigned short* HBh = (unsigned short*)alloc((size_t)NPAD*LH*2);
    unsigned short* HBl = (unsigned short*)alloc((size_t)NPAD*LH*2);
    float* cst  = (float*)alloc((size_t)LH*NPAD*4);                     // 5.18 MB
    float* wr   = (float*)alloc(64*64*4);
    unsigned short* Whi = (unsigned short*)alloc(512*192*2);
    unsigned short* Wlo = (unsigned short*)alloc(512*192*2);
    float* bsum = (float*)alloc(512*4);
    // total ~180 MB

    hipMemsetAsync(cnt, 0, (N_NODES+1)*4, stream);
    hipMemsetAsync(HAh, 0, (size_t)NPAD*LH*2, stream);
    hipMemsetAsync(HAl, 0, (size_t)NPAD*LH*2, stream);
    hipMemsetAsync(cst, 0, (size_t)LH*NPAD*4, stream);

    const int* e_src = ei;
    const int* e_dst = ei + NE;

    k_count  <<<(NE+255)/256, 256, 0, stream>>>(e_dst, cnt);
    k_dinv   <<<(N_NODES+255)/256, 256, 0, stream>>>(cnt, dinv);
    k_scan   <<<1, 1024, 0, stream>>>(cnt, rp, cur);
    k_scatter<<<(NE+255)/256, 256, 0, stream>>>(e_src, e_dst, cur, esrc);

    k_xform  <<<N_NODES*SEQ_T/64, 256, 0, stream>>>(x, gcn_w, hx);
    k_agg    <<<N_NODES, 256, 0, stream>>>(hx, rp, esrc, dinv, gcn_b, g);

    k_wprep  <<<16, 256, 0, stream>>>(conv_w, wr);
    k_wprep2 <<<(512*192+255)/256, 256, 0, stream>>>(w_ih, w_hh, b_ih, b_hh, Whi, Wlo, bsum);
    k_conv   <<<(N_NODES*TS+255)/256, 256, 0, stream>>>(g, wr, conv_b, Xth, Xtl);

    dim3 sgrid(NPAD/128, 8);
    for (int t = 0; t < TS; ++t){
        const unsigned short *Hih = (t & 1) ? HBh : HAh;
        const unsigned short *Hil = (t & 1) ? HBl : HAl;
        unsigned short *Hoh = (t & 1) ? HAh : HBh;
        unsigned short *Hol = (t & 1) ? HAl : HBl;
        k_step<<<sgrid, 256, 0, stream>>>(Xth + (size_t)t*NPAD*CH, Xtl + (size_t)t*NPAD*CH,
                                          Hih, Hil, Hoh, Hol, cst, Whi, Wlo, bsum);
    }
    // TS=31 odd -> last write (t=30, even) went to HB
    k_head<<<(N_NODES+63)/64, 256, 0, stream>>>(HBh, HBl, fc1_w, fc1_b, fc2_w, fc2_b, out);
}

// Round 8
// 1151.181 us; speedup vs baseline: 3.1731x; 1.7077x over previous
//
#include <hip/hip_runtime.h>

#define N_NODES 10000
#define NPAD    10112   // 79 * 128
#define SEQ_T   32
#define NF      128
#define GH      32
#define CH      64
#define LH      128
#define NE      160000
#define TS      31      // conv output / LSTM steps

typedef __attribute__((ext_vector_type(8))) short  bf16x8;
typedef __attribute__((ext_vector_type(4))) float  f32x4;

__device__ __forceinline__ float sig_(float x){ return 1.f/(1.f + expf(-x)); }
__device__ __forceinline__ unsigned short f2bf(float f){
    unsigned int u = __float_as_uint(f);
    u += 0x7FFF + ((u>>16)&1);
    return (unsigned short)(u>>16);
}
__device__ __forceinline__ float bf2f(unsigned short h){
    return __uint_as_float(((unsigned int)h)<<16);
}

// ---------------- degree count ----------------
__global__ void k_count(const int* __restrict__ dst, int* __restrict__ cnt){
    int e = blockIdx.x*256 + threadIdx.x;
    if (e < NE) atomicAdd(&cnt[dst[e]], 1);
}

__global__ void k_dinv(const int* __restrict__ cnt, float* __restrict__ dinv){
    int n = blockIdx.x*256 + threadIdx.x;
    if (n < N_NODES) dinv[n] = rsqrtf((float)(cnt[n] + 1));  // +1 self loop
}

// ---------------- exclusive scan (single block) ----------------
__global__ void k_scan(const int* __restrict__ cnt, int* __restrict__ rp, int* __restrict__ cur){
    __shared__ int buf[1024];
    __shared__ int carry;
    int tid = threadIdx.x;
    if (tid == 0) carry = 0;
    __syncthreads();
    for (int base = 0; base < N_NODES; base += 1024){
        int i = base + tid;
        int v = (i < N_NODES) ? cnt[i] : 0;
        buf[tid] = v;
        __syncthreads();
        for (int off = 1; off < 1024; off <<= 1){
            int t = (tid >= off) ? buf[tid-off] : 0;
            __syncthreads();
            buf[tid] += t;
            __syncthreads();
        }
        int incl = buf[tid];
        int tot  = buf[1023];
        int ex   = carry + incl - v;
        if (i < N_NODES){ rp[i] = ex; cur[i] = ex; }
        __syncthreads();
        if (tid == 0) carry += tot;
        __syncthreads();
    }
    if (tid == 0) rp[N_NODES] = carry;
}

// ---------------- scatter edges into CSR buckets ----------------
__global__ void k_scatter(const int* __restrict__ src, const int* __restrict__ dst,
                          int* __restrict__ cur, int* __restrict__ esrc){
    int e = blockIdx.x*256 + threadIdx.x;
    if (e < NE){
        int p = atomicAdd(&cur[dst[e]], 1);
        esrc[p] = src[e];
    }
}

// ---------------- GCN transform, LDS-tiled ----------------
__global__ __launch_bounds__(256) void k_xform(const float* __restrict__ x,
                                               const float* __restrict__ w,
                                               float* __restrict__ hx){
    __shared__ float xls[64*129];
    int tid = threadIdx.x;
    size_t row0 = (size_t)blockIdx.x * 64;
    #pragma unroll
    for (int it = 0; it < 8; ++it){
        int idx = it*256 + tid;            // 64*32 float4 slots
        int r = idx >> 5, c4 = idx & 31;
        float4 v = *(const float4*)(x + (row0 + r)*NF + c4*4);
        xls[r*129 + c4*4 + 0] = v.x;
        xls[r*129 + c4*4 + 1] = v.y;
        xls[r*129 + c4*4 + 2] = v.z;
        xls[r*129 + c4*4 + 3] = v.w;
    }
    __syncthreads();
    int nl = tid & 63;
    int cg = __builtin_amdgcn_readfirstlane(tid >> 6);   // wave-uniform col group
    float acc[8];
    #pragma unroll
    for (int j = 0; j < 8; ++j) acc[j] = 0.f;
    const float* xrow = xls + nl*129;
    #pragma unroll 4
    for (int k = 0; k < NF; ++k){
        float v = xrow[k];
        const float* wp = w + k*GH + cg*8;   // wave-uniform -> scalar loads
        #pragma unroll
        for (int j = 0; j < 8; ++j) acc[j] += v * wp[j];
    }
    float* ho = hx + (row0 + nl)*GH + cg*8;
    float4 v0; v0.x=acc[0]; v0.y=acc[1]; v0.z=acc[2]; v0.w=acc[3];
    float4 v1; v1.x=acc[4]; v1.y=acc[5]; v1.z=acc[6]; v1.w=acc[7];
    ((float4*)ho)[0] = v0;
    ((float4*)ho)[1] = v1;
}

// ---------------- aggregation: one block per destination node ----------------
__global__ __launch_bounds__(256) void k_agg(const float* __restrict__ hx,
                                             const int* __restrict__ rp,
                                             const int* __restrict__ esrc,
                                             const float* __restrict__ dinv,
                                             const float* __restrict__ bias,
                                             float* __restrict__ g){
    int d  = blockIdx.x;
    int t4 = threadIdx.x;                 // float4 slot 0..255 (1024 floats per node)
    float dv = dinv[d];
    float sn = dv*dv;                      // self-loop norm
    float4 a = ((const float4*)(hx + (size_t)d*1024))[t4];
    float4 acc; acc.x = a.x*sn; acc.y = a.y*sn; acc.z = a.z*sn; acc.w = a.w*sn;
    int beg = rp[d], end = rp[d+1];
    for (int e = beg; e < end; ++e){
        int s = esrc[e];
        float nr = dinv[s]*dv;
        float4 v = ((const float4*)(hx + (size_t)s*1024))[t4];
        acc.x += v.x*nr; acc.y += v.y*nr; acc.z += v.z*nr; acc.w += v.w*nr;
    }
    float4 b4 = ((const float4*)bias)[t4 & 7];   // channel = (t4*4)%32
    acc.x = fmaxf(acc.x + b4.x, 0.f);
    acc.y = fmaxf(acc.y + b4.y, 0.f);
    acc.z = fmaxf(acc.z + b4.z, 0.f);
    acc.w = fmaxf(acc.w + b4.w, 0.f);
    ((float4*)(g + (size_t)d*1024))[t4] = acc;
}

// ---------------- conv weight re-layout: wr[i][o], i in 0..63 ----------------
__global__ void k_wprep(const float* __restrict__ cw, float* __restrict__ wr){
    int idx = blockIdx.x*256 + threadIdx.x;
    if (idx < 64*64){
        int o = idx >> 6, i = idx & 63;
        wr[i*64 + o] = cw[o*64 + (i & 31)*2 + (i >> 5)];
    }
}

// ---------------- LSTM weight prep: row' = j*4+gate order, bf16 hi/lo split ------
__global__ void k_wprep2(const float* __restrict__ wih, const float* __restrict__ whh,
                         const float* __restrict__ bih, const float* __restrict__ bhh,
                         unsigned short* __restrict__ Whi, unsigned short* __restrict__ Wlo,
                         float* __restrict__ bsum){
    int e = blockIdx.x*256 + threadIdx.x;   // 512*192 = 98304
    if (e >= 512*192) return;
    int rp = e / 192, k = e - rp*192;
    int j = rp >> 2, gt = rp & 3, R = gt*128 + j;
    float v = (k < 64) ? wih[R*64 + k] : whh[R*128 + (k-64)];
    unsigned short hi = f2bf(v);
    Whi[e] = hi;
    Wlo[e] = f2bf(v - bf2f(hi));
    if (k == 0) bsum[rp] = bih[R] + bhh[R];
}

// ---------------- conv1d, thread-per-row; writes bf16 hi/lo node-major Xt --------
__global__ __launch_bounds__(256) void k_conv(const float* __restrict__ g,
                                              const float* __restrict__ wr,
                                              const float* __restrict__ cb,
                                              unsigned short* __restrict__ Xth,
                                              unsigned short* __restrict__ Xtl){
    int m = blockIdx.x*256 + threadIdx.x;              // row = n*31 + t
    if (m >= N_NODES*TS) return;
    int n = m / TS;
    int t = m - n*TS;
    const float4* ar = (const float4*)(g + ((size_t)n*SEQ_T + t)*GH);
    float acc[CH];
    #pragma unroll
    for (int o = 0; o < CH; ++o) acc[o] = 0.f;
    for (int f4 = 0; f4 < 16; ++f4){
        float4 a = ar[f4];
        #pragma unroll
        for (int k = 0; k < 4; ++k){
            float av = ((const float*)&a)[k];
            const float* wrow = wr + (f4*4 + k)*CH;
            #pragma unroll
            for (int o = 0; o < CH; ++o) acc[o] += av * wrow[o];
        }
    }
    size_t base = ((size_t)t*NPAD + n)*CH;
    #pragma unroll
    for (int o4 = 0; o4 < CH/4; ++o4){
        ushort4 vh, vl;
        float v0 = fmaxf(acc[o4*4+0] + cb[o4*4+0], 0.f);
        float v1 = fmaxf(acc[o4*4+1] + cb[o4*4+1], 0.f);
        float v2 = fmaxf(acc[o4*4+2] + cb[o4*4+2], 0.f);
        float v3 = fmaxf(acc[o4*4+3] + cb[o4*4+3], 0.f);
        vh.x = f2bf(v0); vl.x = f2bf(v0 - bf2f(vh.x));
        vh.y = f2bf(v1); vl.y = f2bf(v1 - bf2f(vh.y));
        vh.z = f2bf(v2); vl.z = f2bf(v2 - bf2f(vh.z));
        vh.w = f2bf(v3); vl.w = f2bf(v3 - bf2f(vh.w));
        *(ushort4*)(Xth + base + o4*4) = vh;
        *(ushort4*)(Xtl + base + o4*4) = vl;
    }
}

// ---------------- MFMA LSTM step, LDS-staged B (split-bf16, 3 terms) -------------
// grid (NPAD/64=158, 4), block 256 = 4 waves.
// Block: nodes nb*64..+63, rows' by*128..+127 (2 sub-iters of 4 waves x 16 rows).
// B (Xt k<64, H k>=64) staged in LDS hi+lo with XOR swizzle; A (W) from L2.
// C tile (m89): col(n) = l&15, row' = (l>>4)*4 + reg -> reg = gate, j = r0/4 + l>>4.
__global__ __launch_bounds__(256) void k_step(const unsigned short* __restrict__ Xth,
                                              const unsigned short* __restrict__ Xtl,
                                              const unsigned short* __restrict__ Hih,
                                              const unsigned short* __restrict__ Hil,
                                              unsigned short* __restrict__ Hoh,
                                              unsigned short* __restrict__ Hol,
                                              float* __restrict__ cst,        // [128][NPAD]
                                              const unsigned short* __restrict__ Whi,
                                              const unsigned short* __restrict__ Wlo,
                                              const float* __restrict__ bsum){
    __shared__ unsigned short lbh[64*192];   // B hi, swizzled
    __shared__ unsigned short lbl[64*192];   // B lo, swizzled
    __shared__ unsigned short lho[64*16*2];  // h out staging: hi | lo
    int tid  = threadIdx.x;
    int lane = tid & 63, wv = tid >> 6;
    int n0   = blockIdx.x * 64;

    // ---- stage B: Xt part (k-groups 0..7) ----
    #pragma unroll
    for (int it = 0; it < 2; ++it){
        int idx = it*256 + tid;              // 512 = 64 nodes x 8 groups
        int nl = idx >> 3, g = idx & 7;
        int slot = g ^ (nl & 7);
        size_t src = (size_t)(n0 + nl)*64 + g*8;
        *(bf16x8*)(lbh + nl*192 + slot*8) = *(const bf16x8*)(Xth + src);
        *(bf16x8*)(lbl + nl*192 + slot*8) = *(const bf16x8*)(Xtl + src);
    }
    // ---- stage B: H part (k-groups 8..23) ----
    #pragma unroll
    for (int it = 0; it < 4; ++it){
        int idx = it*256 + tid;              // 1024 = 64 nodes x 16 groups
        int nl = idx >> 4, gh = idx & 15;
        int kg8 = 8 + gh;
        int slot = (kg8 & ~7) | ((kg8 & 7) ^ (nl & 7));
        size_t src = (size_t)(n0 + nl)*128 + gh*8;
        *(bf16x8*)(lbh + nl*192 + slot*8) = *(const bf16x8*)(Hih + src);
        *(bf16x8*)(lbl + nl*192 + slot*8) = *(const bf16x8*)(Hil + src);
    }
    __syncthreads();

    int ar = lane & 15;                      // A row within tile / B node within tile
    int kg = lane >> 4;                      // k-group quarter

    #pragma unroll
    for (int by2 = 0; by2 < 2; ++by2){
        int r0 = blockIdx.y*128 + by2*64 + wv*16;
        const unsigned short* Ah = Whi + (size_t)(r0 + ar)*192 + kg*8;
        const unsigned short* Al = Wlo + (size_t)(r0 + ar)*192 + kg*8;

        f32x4 acc[4];
        #pragma unroll
        for (int i = 0; i < 4; ++i) acc[i] = (f32x4){0.f,0.f,0.f,0.f};

        #pragma unroll
        for (int kc = 0; kc < 6; ++kc){
            bf16x8 ahi = *(const bf16x8*)(Ah + kc*32);
            bf16x8 alo = *(const bf16x8*)(Al + kc*32);
            int kg8 = kc*4 + kg;
            int sbase = (kg8 & ~7)*8;
            int sxor  = (kg8 & 7);
            #pragma unroll
            for (int nt = 0; nt < 4; ++nt){
                int nloc = nt*16 + ar;
                int off = nloc*192 + sbase + ((sxor ^ (nloc & 7))*8);
                bf16x8 bhi = *(const bf16x8*)(lbh + off);
                bf16x8 blo = *(const bf16x8*)(lbl + off);
                acc[nt] = __builtin_amdgcn_mfma_f32_16x16x32_bf16(ahi, bhi, acc[nt], 0, 0, 0);
                acc[nt] = __builtin_amdgcn_mfma_f32_16x16x32_bf16(ahi, blo, acc[nt], 0, 0, 0);
                acc[nt] = __builtin_amdgcn_mfma_f32_16x16x32_bf16(alo, bhi, acc[nt], 0, 0, 0);
            }
        }

        int jl = wv*4 + kg;                  // local j (0..15)
        int jcol0 = blockIdx.y*32 + by2*16;
        int j  = jcol0 + jl;                 // global j
        float4 bs = ((const float4*)bsum)[j];
        #pragma unroll
        for (int nt = 0; nt < 4; ++nt){
            int nloc = nt*16 + ar;
            int n = n0 + nloc;
            float ig = sig_(acc[nt][0] + bs.x);
            float fg = sig_(acc[nt][1] + bs.y);
            float gv = tanhf(acc[nt][2] + bs.z);
            float og = sig_(acc[nt][3] + bs.w);
            float cold = cst[(size_t)j*NPAD + n];
            float cn = fg*cold + ig*gv;
            cst[(size_t)j*NPAD + n] = cn;
            float h = og * tanhf(cn);
            unsigned short hh = f2bf(h);
            unsigned short hl = f2bf(h - bf2f(hh));
            lho[nloc*16 + jl]        = hh;
            lho[1024 + nloc*16 + jl] = hl;
        }
        __syncthreads();
        // coalesced write-out: 256 x 16B chunks
        {
            int nl2  = tid >> 2;
            int q    = tid & 3;
            int part = q >> 1, half = q & 1;
            const uint4 v = *(const uint4*)(lho + part*1024 + nl2*16 + half*8);
            unsigned short* dst = (part ? Hol : Hoh);
            *(uint4*)(dst + (size_t)(n0 + nl2)*128 + jcol0 + half*8) = v;
        }
        __syncthreads();
    }
}

// ---------------- MLP head: 16 nodes/block, 625 blocks ----------------
__global__ __launch_bounds__(256) void k_head(const unsigned short* __restrict__ Hh,
                                              const unsigned short* __restrict__ Hl,
                                              const float* __restrict__ w1,   // [128][64]
                                              const float* __restrict__ b1,
                                              const float* __restrict__ w2,   // [64][128]
                                              const float* __restrict__ b2,
                                              float* __restrict__ out){       // [N][128]
    __shared__ float hsl[16*129];
    __shared__ float y1 [16*65];
    int tid = threadIdx.x;
    int n0  = blockIdx.x*16;
    #pragma unroll
    for (int it = 0; it < 8; ++it){
        int idx = it*256 + tid;            // 2048 = 16 x 128
        int nl = idx >> 7, k = idx & 127;
        int n = n0 + nl;
        float v = 0.f;
        if (n < N_NODES) v = bf2f(Hh[(size_t)n*128 + k]) + bf2f(Hl[(size_t)n*128 + k]);
        hsl[nl*129 + k] = v;
    }
    __syncthreads();
    #pragma unroll
    for (int rep = 0; rep < 4; ++rep){
        int id = rep*256 + tid;            // 1024 = 16 x 64
        int nl = id >> 6, c = id & 63;
        float a = b1[c];
        #pragma unroll 4
        for (int k = 0; k < 128; ++k) a += hsl[nl*129 + k] * w1[k*64 + c];
        y1[nl*65 + c] = fmaxf(a, 0.f);
    }
    __syncthreads();
    #pragma unroll
    for (int rep = 0; rep < 8; ++rep){
        int id = rep*256 + tid;            // 2048 = 16 x 128
        int nl = id >> 7, o = id & 127;
        int n = n0 + nl;
        float a = b2[o];
        #pragma unroll 4
        for (int k = 0; k < 64; ++k) a += y1[nl*65 + k] * w2[k*128 + o];
        if (n < N_NODES) out[(size_t)n*128 + o] = a;
    }
}

extern "C" void kernel_launch(void* const* d_in, const int* in_sizes, int n_in,
                              void* d_out, int out_size, void* d_ws, size_t ws_size,
                              hipStream_t stream){
    const float* x      = (const float*)d_in[0];
    const int*   ei     = (const int*)  d_in[1];
    const float* gcn_w  = (const float*)d_in[2];
    const float* gcn_b  = (const float*)d_in[3];
    const float* conv_w = (const float*)d_in[4];
    const float* conv_b = (const float*)d_in[5];
    const float* w_ih   = (const float*)d_in[6];
    const float* w_hh   = (const float*)d_in[7];
    const float* b_ih   = (const float*)d_in[8];
    const float* b_hh   = (const float*)d_in[9];
    const float* fc1_w  = (const float*)d_in[10];
    const float* fc1_b  = (const float*)d_in[11];
    const float* fc2_w  = (const float*)d_in[12];
    const float* fc2_b  = (const float*)d_in[13];
    float* out = (float*)d_out;

    char* p = (char*)d_ws;
    auto alloc = [&](size_t bytes)->void*{ void* r = p; p += (bytes + 255) & ~(size_t)255; return r; };
    float* dinv = (float*)alloc(N_NODES*4);
    int*   cnt  = (int*)  alloc((N_NODES+1)*4);
    int*   rp   = (int*)  alloc((N_NODES+1)*4);
    int*   cur  = (int*)  alloc(N_NODES*4);
    int*   esrc = (int*)  alloc(NE*4);
    float* hx   = (float*)alloc((size_t)N_NODES*SEQ_T*GH*4);          // 40.96 MB
    float* g    = (float*)alloc((size_t)N_NODES*SEQ_T*GH*4);          // 40.96 MB
    unsigned short* Xth = (unsigned short*)alloc((size_t)TS*NPAD*CH*2); // 40.1 MB
    unsigned short* Xtl = (unsigned short*)alloc((size_t)TS*NPAD*CH*2); // 40.1 MB
    unsigned short* HAh = (unsigned short*)alloc((size_t)NPAD*LH*2);    // 2.59 MB
    unsigned short* HAl = (unsigned short*)alloc((size_t)NPAD*LH*2);
    unsigned short* HBh = (unsigned short*)alloc((size_t)NPAD*LH*2);
    unsigned short* HBl = (unsigned short*)alloc((size_t)NPAD*LH*2);
    float* cst  = (float*)alloc((size_t)LH*NPAD*4);                     // 5.18 MB
    float* wr   = (float*)alloc(64*64*4);
    unsigned short* Whi = (unsigned short*)alloc(512*192*2);
    unsigned short* Wlo = (unsigned short*)alloc(512*192*2);
    float* bsum = (float*)alloc(512*4);
    // total ~180 MB

    hipMemsetAsync(cnt, 0, (N_NODES+1)*4, stream);
    hipMemsetAsync(HAh, 0, (size_t)NPAD*LH*2, stream);
    hipMemsetAsync(HAl, 0, (size_t)NPAD*LH*2, stream);
    hipMemsetAsync(cst, 0, (size_t)LH*NPAD*4, stream);

    const int* e_src = ei;
    const int* e_dst = ei + NE;

    k_count  <<<(NE+255)/256, 256, 0, stream>>>(e_dst, cnt);
    k_dinv   <<<(N_NODES+255)/256, 256, 0, stream>>>(cnt, dinv);
    k_scan   <<<1, 1024, 0, stream>>>(cnt, rp, cur);
    k_scatter<<<(NE+255)/256, 256, 0, stream>>>(e_src, e_dst, cur, esrc);

    k_xform  <<<N_NODES*SEQ_T/64, 256, 0, stream>>>(x, gcn_w, hx);
    k_agg    <<<N_NODES, 256, 0, stream>>>(hx, rp, esrc, dinv, gcn_b, g);

    k_wprep  <<<16, 256, 0, stream>>>(conv_w, wr);
    k_wprep2 <<<(512*192+255)/256, 256, 0, stream>>>(w_ih, w_hh, b_ih, b_hh, Whi, Wlo, bsum);
    k_conv   <<<(N_NODES*TS+255)/256, 256, 0, stream>>>(g, wr, conv_b, Xth, Xtl);

    dim3 sgrid(NPAD/64, 4);
    for (int t = 0; t < TS; ++t){
        const unsigned short *Hih = (t & 1) ? HBh : HAh;
        const unsigned short *Hil = (t & 1) ? HBl : HAl;
        unsigned short *Hoh = (t & 1) ? HAh : HBh;
        unsigned short *Hol = (t & 1) ? HAl : HBl;
        k_step<<<sgrid, 256, 0, stream>>>(Xth + (size_t)t*NPAD*CH, Xtl + (size_t)t*NPAD*CH,
                                          Hih, Hil, Hoh, Hol, cst, Whi, Wlo, bsum);
    }
    // TS=31 odd -> last write (t=30, even) went to HB
    k_head<<<(N_NODES+15)/16, 256, 0, stream>>>(HBh, HBl, fc1_w, fc1_b, fc2_w, fc2_b, out);
}